// Round 1
// baseline (1428.322 us; speedup 1.0000x reference)
//
#include <hip/hip_runtime.h>
#include <stdint.h>

#define NN 16384   // nodes
#define NC 16      // colors
#define NB 64      // graphs

// open-addressing hash table: h (64-bit) -> min node index
#define HSIZE 65536
#define HMASK 65535
#define HSENT 0xFFFFFFFFFFFFFFFFull
#define HGOLD 0x9E3779B97F4A7C15ull

typedef unsigned int vuint4 __attribute__((ext_vector_type(4)));  // native vec for nontemporal builtin

struct Mults { unsigned long long m[17]; };

__device__ __forceinline__ void htab_insert(unsigned long long* __restrict__ hk,
                                            int* __restrict__ hv,
                                            unsigned long long key, int idx) {
  if (key == HSENT) key -= 1;                    // sentinel nudge (prob ~2^-64, same class risk as ref's 64-bit hash)
  unsigned slot = (unsigned)((key * HGOLD) >> 48);
  for (;;) {
    unsigned long long old = atomicCAS(&hk[slot], HSENT, key);
    if (old == HSENT || old == key) { atomicMin(&hv[slot], idx); return; }
    slot = (slot + 1) & HMASK;
  }
}

// ---------------- kernels ----------------

// Build per-64-column color bitmasks matching the ballot bit layout of k_hist,
// zero scount, zero the 4 MB cnt buffer, and init the hash table.
// grid = 256 x 256 threads.
__global__ __launch_bounds__(256) void k_init(const int* __restrict__ x,
                                              unsigned long long* __restrict__ table,
                                              int* __restrict__ scount,
                                              int* __restrict__ cnt,
                                              unsigned long long* __restrict__ hk,
                                              int* __restrict__ hv) {
  int idx = blockIdx.x * 256 + threadIdx.x;        // [0, 65536)
  if (idx == 0) *scount = 0;
  if (idx < 4096) {
    int c = idx & 15, k = (idx >> 4) & 3, chunk = idx >> 6;
    unsigned long long m = 0ull;
    for (int l = 0; l < 64; ++l) {
      int col = chunk * 256 + l * 4 + k;
      if (x[col] == c) m |= (1ull << l);
    }
    table[idx] = m;
  }
  // hash table init: 65536 slots, one per thread
  hk[idx] = HSENT;
  hv[idx] = 0x7fffffff;
  // zero cnt: 1M ints = 262144 int4; 65536 threads x 4 int4 each
  int4 z = {0, 0, 0, 0};
  int4* c4 = (int4*)cnt;
  #pragma unroll
  for (int r = 0; r < 4; ++r) c4[(size_t)idx * 4 + r] = z;
}

// One wave per row: neighbor color histogram via ballots + mask popcounts.
// Epilogue computes the 64-bit polynomial hash, rowsum (isolation suspects),
// inserts (h, row) into the hash table for non-suspect rows, and inits iso.
// adj is streamed once -> nontemporal loads.
__global__ __launch_bounds__(256) void k_hist(const float* __restrict__ adj,
                                              const unsigned long long* __restrict__ table,
                                              const int* __restrict__ x,
                                              Mults M,
                                              unsigned long long* __restrict__ h,
                                              int* __restrict__ iso,
                                              int* __restrict__ suspects,
                                              int* __restrict__ scount,
                                              unsigned long long* __restrict__ hk,
                                              int* __restrict__ hv) {
  int wave = threadIdx.x >> 6;
  int lane = threadIdx.x & 63;
  int row  = blockIdx.x * 4 + wave;
  int xv   = x[row];
  const vuint4* rowp = (const vuint4*)(adj + (size_t)row * NN);
  int c = lane & 15;
  int k = lane >> 4;                               // k-slice 0..3
  const unsigned long long* tk = table + (k * 16 + c);
  int cnt = 0;
  #pragma unroll 4
  for (int chunk = 0; chunk < 64; ++chunk) {
    vuint4 v = __builtin_nontemporal_load(&rowp[chunk * 64 + lane]);  // 1 KiB/wave, coalesced, streamed
    unsigned long long tm = tk[chunk * 64];
    unsigned long long b0 = __ballot(v.x != 0u);
    unsigned long long b1 = __ballot(v.y != 0u);
    unsigned long long b2 = __ballot(v.z != 0u);
    unsigned long long b3 = __ballot(v.w != 0u);
    unsigned long long m = (k & 2) ? ((k & 1) ? b3 : b2) : ((k & 1) ? b1 : b0);
    cnt += __popcll(m & tm);
  }
  // fold the 4 k-slices: every lane now holds hist[lane & 15]
  cnt += __shfl_xor(cnt, 16, 64);
  cnt += __shfl_xor(cnt, 32, 64);
  // rowsum (within each 16-lane group = sum over all 16 colors)
  int rs = cnt;
  rs += __shfl_xor(rs, 1, 64);
  rs += __shfl_xor(rs, 2, 64);
  rs += __shfl_xor(rs, 4, 64);
  rs += __shfl_xor(rs, 8, 64);
  // polynomial hash: sum over c of hist[c] * M[c+1]
  unsigned long long hl = (unsigned long long)(long long)cnt * M.m[(lane & 15) + 1];
  hl += __shfl_xor(hl, 1, 64);
  hl += __shfl_xor(hl, 2, 64);
  hl += __shfl_xor(hl, 4, 64);
  hl += __shfl_xor(hl, 8, 64);
  if (lane == 0) {
    unsigned long long hf = hl + (unsigned long long)(long long)xv * M.m[0];
    h[row] = hf;
    if (rs == 0) {
      int s = atomicAdd(scount, 1);
      suspects[s] = row;                 // h not final until colcheck; insert deferred there
    } else {
      htab_insert(hk, hv, hf, row);
    }
  }
  if (lane == 1) iso[row] = 0;
}

// Check columns of suspect nodes only (exits immediately if no suspects).
// Confirmed isolates get iso=1; unconfirmed suspects get their h inserted
// into the hash table (their h from k_hist is final).
__global__ __launch_bounds__(256) void k_colcheck(const float* __restrict__ adj,
                                                  const int* __restrict__ suspects,
                                                  const int* __restrict__ scount,
                                                  int* __restrict__ iso,
                                                  const unsigned long long* __restrict__ h,
                                                  unsigned long long* __restrict__ hk,
                                                  int* __restrict__ hv) {
  __shared__ int red[256];
  int nsus = *scount;
  for (int u = blockIdx.x; u < nsus; u += gridDim.x) {
    int col = suspects[u];
    int any = 0;
    for (int r = threadIdx.x; r < NN; r += 256)
      any |= (adj[(size_t)r * NN + col] != 0.0f);
    red[threadIdx.x] = any;
    __syncthreads();
    for (int s = 128; s > 0; s >>= 1) {
      if (threadIdx.x < s) red[threadIdx.x] |= red[threadIdx.x + s];
      __syncthreads();
    }
    if (threadIdx.x == 0) {
      if (red[0] == 0) iso[col] = 1;
      else             htab_insert(hk, hv, h[col], col);
    }
    __syncthreads();
  }
}

// Single block: hash-table lookup gives firsts[i] = min{ j : h[j]==h[i] } in O(1)
// per node (replaces the old O(N^2) k_firsts dispatch). Then rank = prefix sum
// of is_first (insertion order), colors, out_colors, and per-graph histogram
// counts in one pass. Wave-level shfl scan: 2 barriers.
__global__ __launch_bounds__(1024) void k_scan(const int* __restrict__ iso,
                                               const unsigned long long* __restrict__ h,
                                               const unsigned long long* __restrict__ hk,
                                               const int* __restrict__ hv,
                                               const int* __restrict__ batch,
                                               float* __restrict__ out_colors,
                                               int* __restrict__ cnt) {
  __shared__ int rank_lds[NN];     // 64 KiB
  __shared__ int wsum[16];
  int t = threadIdx.x;
  int lane = t & 63, wv = t >> 6;
  int base = t * 16;
  int fidx[16];
  int loc[16];
  int s = 0;
  #pragma unroll
  for (int u = 0; u < 16; ++u) {
    int i = base + u;
    int f = -1;
    if (!iso[i]) {
      unsigned long long key = h[i];
      if (key == HSENT) key -= 1;                  // must match insert-side nudge
      unsigned slot = (unsigned)((key * HGOLD) >> 48);
      unsigned long long kk = hk[slot];
      while (kk != key) { slot = (slot + 1) & HMASK; kk = hk[slot]; }
      f = hv[slot];                                // guaranteed present & final
    }
    fidx[u] = f;
    int isf = (f == i);
    s += isf;
    loc[u] = s;                    // inclusive within segment
  }
  // wave-inclusive scan of s
  int incl = s;
  #pragma unroll
  for (int off = 1; off < 64; off <<= 1) {
    int v = __shfl_up(incl, off, 64);
    if (lane >= off) incl += v;
  }
  if (lane == 63) wsum[wv] = incl;
  __syncthreads();
  if (t == 0) {
    int acc = 0;
    #pragma unroll
    for (int w = 0; w < 16; ++w) { int v = wsum[w]; wsum[w] = acc; acc += v; }
  }
  __syncthreads();
  int excl = wsum[wv] + incl - s;  // exclusive prefix of this thread's segment
  #pragma unroll
  for (int u = 0; u < 16; ++u) rank_lds[base + u] = excl + loc[u];
  __syncthreads();
  #pragma unroll
  for (int u = 0; u < 16; ++u) {
    int i = base + u;
    int c = (fidx[u] < 0) ? 0 : rank_lds[fidx[u]];
    out_colors[i] = (float)c;
    if (c > 0) atomicAdd(&cnt[(size_t)batch[i] * NN + (c - 1)], 1);
  }
}

__global__ __launch_bounds__(256) void k_norm(const int* __restrict__ cnt,
                                              float* __restrict__ out) {
  __shared__ float red[256];
  int b = blockIdx.x;
  const int4* c4 = (const int4*)(cnt + (size_t)b * NN);
  float4* o4 = (float4*)(out + (size_t)b * NN);
  float ss = 0.0f;
  for (int j = threadIdx.x; j < NN / 4; j += 256) {
    int4 v = c4[j];
    float4 f = {(float)v.x, (float)v.y, (float)v.z, (float)v.w};
    ss += f.x * f.x + f.y * f.y + f.z * f.z + f.w * f.w;
  }
  red[threadIdx.x] = ss;
  __syncthreads();
  for (int s = 128; s > 0; s >>= 1) {
    if (threadIdx.x < s) red[threadIdx.x] += red[threadIdx.x + s];
    __syncthreads();
  }
  float inv = 1.0f / sqrtf(red[0]);
  for (int j = threadIdx.x; j < NN / 4; j += 256) {
    int4 v = c4[j];
    float4 f = {(float)v.x * inv, (float)v.y * inv, (float)v.z * inv, (float)v.w * inv};
    o4[j] = f;
  }
}

// ---------------- host: numpy RandomState(42) MULTS replication ----------------

struct MTState { uint32_t mt[624]; int idx; };

static void mt_seed(MTState& s, uint32_t seed) {
  s.mt[0] = seed;
  for (int i = 1; i < 624; ++i)
    s.mt[i] = 1812433253u * (s.mt[i - 1] ^ (s.mt[i - 1] >> 30)) + (uint32_t)i;
  s.idx = 624;
}

static uint32_t mt_next(MTState& s) {
  if (s.idx >= 624) {
    for (int i = 0; i < 624; ++i) {
      uint32_t y = (s.mt[i] & 0x80000000u) | (s.mt[(i + 1) % 624] & 0x7fffffffu);
      uint32_t nx = s.mt[(i + 397) % 624] ^ (y >> 1);
      if (y & 1u) nx ^= 2567483615u;
      s.mt[i] = nx;
    }
    s.idx = 0;
  }
  uint32_t y = s.mt[s.idx++];
  y ^= y >> 11;
  y ^= (y << 7) & 2636928640u;
  y ^= (y << 15) & 4022730752u;
  y ^= y >> 18;
  return y;
}

static uint64_t mt_next64(MTState& s) {
  uint64_t hi = mt_next(s);
  uint64_t lo = mt_next(s);
  return (hi << 32) | lo;
}

// ---------------- launch ----------------

extern "C" void kernel_launch(void* const* d_in, const int* in_sizes, int n_in,
                              void* d_out, int out_size, void* d_ws, size_t ws_size,
                              hipStream_t stream) {
  const int*   x     = (const int*)d_in[0];
  const float* adj   = (const float*)d_in[1];
  const int*   batch = (const int*)d_in[2];
  float* out_hist   = (float*)d_out;                    // [NB, NN]
  float* out_colors = out_hist + (size_t)NB * NN;       // [NN]

  char* ws = (char*)d_ws;
  int*                cnt      = (int*)(ws + 0);          // 4 MiB
  int*                scount   = (int*)(ws + 4194304);    // 256 B
  int*                suspects = (int*)(ws + 4194560);    // 64 KiB
  unsigned long long* h        = (unsigned long long*)(ws + 4260096); // 128 KiB
  int*                iso      = (int*)(ws + 4391168);    // 64 KiB
  unsigned long long* table    = (unsigned long long*)(ws + 4456704); // 32 KiB
  unsigned long long* hk       = (unsigned long long*)(ws + 4489216); // 512 KiB hash keys
  int*                hv       = (int*)(ws + 5013504);    // 256 KiB hash values (min idx)

  // Replicate np.random.RandomState(42).randint(1, 2**62, 17) << 1 | 1
  // (legacy masked rejection: mask = 2^62-1, accept <= 2^62-2, high word first)
  Mults M;
  {
    MTState st;
    mt_seed(st, 42u);
    const uint64_t mask62 = (1ull << 62) - 1ull;
    const uint64_t rng    = (1ull << 62) - 2ull;
    for (int i = 0; i < 17; ++i) {
      uint64_t v;
      do { v = mt_next64(st) & mask62; } while (v > rng);
      M.m[i] = ((1ull + v) << 1) | 1ull;
    }
  }

  k_init<<<256, 256, 0, stream>>>(x, table, scount, cnt, hk, hv);
  k_hist<<<NN / 4, 256, 0, stream>>>(adj, table, x, M, h, iso, suspects, scount, hk, hv);
  k_colcheck<<<64, 256, 0, stream>>>(adj, suspects, scount, iso, h, hk, hv);
  k_scan<<<1, 1024, 0, stream>>>(iso, h, hk, hv, batch, out_colors, cnt);
  k_norm<<<NB, 256, 0, stream>>>(cnt, out_hist);
}

// Round 2
// 1360.918 us; speedup vs baseline: 1.0495x; 1.0495x over previous
//
#include <hip/hip_runtime.h>
#include <stdint.h>

#define NN 16384   // nodes
#define NC 16      // colors
#define NB 64      // graphs

// open-addressing hash table: h (64-bit) -> min node index
#define HSIZE 65536
#define HMASK 65535
#define HSENT 0xFFFFFFFFFFFFFFFFull
#define HGOLD 0x9E3779B97F4A7C15ull

typedef unsigned int vuint4 __attribute__((ext_vector_type(4)));  // native vec for nontemporal builtin

struct Mults { unsigned long long m[17]; };

__device__ __forceinline__ void htab_insert(unsigned long long* __restrict__ hk,
                                            int* __restrict__ hv,
                                            unsigned long long key, int idx) {
  if (key == HSENT) key -= 1;                    // sentinel nudge (prob ~2^-64, same class risk as ref's 64-bit hash)
  unsigned slot = (unsigned)((key * HGOLD) >> 48);
  for (;;) {
    unsigned long long old = atomicCAS(&hk[slot], HSENT, key);
    if (old == HSENT || old == key) { atomicMin(&hv[slot], idx); return; }
    slot = (slot + 1) & HMASK;
  }
}

// ---------------- kernels ----------------

// Build per-64-column color bitmasks matching the ballot bit layout of k_hist,
// zero scount, zero the 4 MB cnt buffer, and init the hash table.
// grid = 256 x 256 threads.
__global__ __launch_bounds__(256) void k_init(const int* __restrict__ x,
                                              unsigned long long* __restrict__ table,
                                              int* __restrict__ scount,
                                              int* __restrict__ cnt,
                                              unsigned long long* __restrict__ hk,
                                              int* __restrict__ hv) {
  int idx = blockIdx.x * 256 + threadIdx.x;        // [0, 65536)
  if (idx == 0) *scount = 0;
  if (idx < 4096) {
    int c = idx & 15, k = (idx >> 4) & 3, chunk = idx >> 6;
    unsigned long long m = 0ull;
    for (int l = 0; l < 64; ++l) {
      int col = chunk * 256 + l * 4 + k;
      if (x[col] == c) m |= (1ull << l);
    }
    table[idx] = m;
  }
  // hash table init: 65536 slots, one per thread
  hk[idx] = HSENT;
  hv[idx] = 0x7fffffff;
  // zero cnt: 1M ints = 262144 int4; 65536 threads x 4 int4 each
  int4 z = {0, 0, 0, 0};
  int4* c4 = (int4*)cnt;
  #pragma unroll
  for (int r = 0; r < 4; ++r) c4[(size_t)idx * 4 + r] = z;
}

// One wave per row: neighbor color histogram via ballots + mask popcounts.
// Epilogue computes the 64-bit polynomial hash, rowsum (isolation suspects),
// inserts (h, row) into the hash table for non-suspect rows, and inits iso.
// adj is streamed once -> nontemporal loads.
__global__ __launch_bounds__(256) void k_hist(const float* __restrict__ adj,
                                              const unsigned long long* __restrict__ table,
                                              const int* __restrict__ x,
                                              Mults M,
                                              unsigned long long* __restrict__ h,
                                              int* __restrict__ iso,
                                              int* __restrict__ suspects,
                                              int* __restrict__ scount,
                                              unsigned long long* __restrict__ hk,
                                              int* __restrict__ hv) {
  int wave = threadIdx.x >> 6;
  int lane = threadIdx.x & 63;
  int row  = blockIdx.x * 4 + wave;
  int xv   = x[row];
  const vuint4* rowp = (const vuint4*)(adj + (size_t)row * NN);
  int c = lane & 15;
  int k = lane >> 4;                               // k-slice 0..3
  const unsigned long long* tk = table + (k * 16 + c);
  int cnt = 0;
  #pragma unroll 4
  for (int chunk = 0; chunk < 64; ++chunk) {
    vuint4 v = __builtin_nontemporal_load(&rowp[chunk * 64 + lane]);  // 1 KiB/wave, coalesced, streamed
    unsigned long long tm = tk[chunk * 64];
    unsigned long long b0 = __ballot(v.x != 0u);
    unsigned long long b1 = __ballot(v.y != 0u);
    unsigned long long b2 = __ballot(v.z != 0u);
    unsigned long long b3 = __ballot(v.w != 0u);
    unsigned long long m = (k & 2) ? ((k & 1) ? b3 : b2) : ((k & 1) ? b1 : b0);
    cnt += __popcll(m & tm);
  }
  // fold the 4 k-slices: every lane now holds hist[lane & 15]
  cnt += __shfl_xor(cnt, 16, 64);
  cnt += __shfl_xor(cnt, 32, 64);
  // rowsum (within each 16-lane group = sum over all 16 colors)
  int rs = cnt;
  rs += __shfl_xor(rs, 1, 64);
  rs += __shfl_xor(rs, 2, 64);
  rs += __shfl_xor(rs, 4, 64);
  rs += __shfl_xor(rs, 8, 64);
  // polynomial hash: sum over c of hist[c] * M[c+1]
  unsigned long long hl = (unsigned long long)(long long)cnt * M.m[(lane & 15) + 1];
  hl += __shfl_xor(hl, 1, 64);
  hl += __shfl_xor(hl, 2, 64);
  hl += __shfl_xor(hl, 4, 64);
  hl += __shfl_xor(hl, 8, 64);
  if (lane == 0) {
    unsigned long long hf = hl + (unsigned long long)(long long)xv * M.m[0];
    h[row] = hf;
    if (rs == 0) {
      int s = atomicAdd(scount, 1);
      suspects[s] = row;                 // h not final until colcheck; insert deferred there
    } else {
      htab_insert(hk, hv, hf, row);
    }
  }
  if (lane == 1) iso[row] = 0;
}

// Check columns of suspect nodes only (exits immediately if no suspects).
// Confirmed isolates get iso=1; unconfirmed suspects get their h inserted
// into the hash table (their h from k_hist is final).
__global__ __launch_bounds__(256) void k_colcheck(const float* __restrict__ adj,
                                                  const int* __restrict__ suspects,
                                                  const int* __restrict__ scount,
                                                  int* __restrict__ iso,
                                                  const unsigned long long* __restrict__ h,
                                                  unsigned long long* __restrict__ hk,
                                                  int* __restrict__ hv) {
  __shared__ int red[256];
  int nsus = *scount;
  for (int u = blockIdx.x; u < nsus; u += gridDim.x) {
    int col = suspects[u];
    int any = 0;
    for (int r = threadIdx.x; r < NN; r += 256)
      any |= (adj[(size_t)r * NN + col] != 0.0f);
    red[threadIdx.x] = any;
    __syncthreads();
    for (int s = 128; s > 0; s >>= 1) {
      if (threadIdx.x < s) red[threadIdx.x] |= red[threadIdx.x + s];
      __syncthreads();
    }
    if (threadIdx.x == 0) {
      if (red[0] == 0) iso[col] = 1;
      else             htab_insert(hk, hv, h[col], col);
    }
    __syncthreads();
  }
}

// Grid-parallel hash lookup: firsts[i] = min{ j : h[j]==h[i] } via one O(1)
// probe chain per node; -1 for isolates. 16384 threads across 64 blocks hide
// the scattered-load latency that a single-block probe loop cannot.
__global__ __launch_bounds__(256) void k_lookup(const int* __restrict__ iso,
                                                const unsigned long long* __restrict__ h,
                                                const unsigned long long* __restrict__ hk,
                                                const int* __restrict__ hv,
                                                int* __restrict__ firsts) {
  int i = blockIdx.x * 256 + threadIdx.x;
  int f = -1;
  if (!iso[i]) {
    unsigned long long key = h[i];
    if (key == HSENT) key -= 1;                  // must match insert-side nudge
    unsigned slot = (unsigned)((key * HGOLD) >> 48);
    unsigned long long kk = hk[slot];
    while (kk != key) { slot = (slot + 1) & HMASK; kk = hk[slot]; }
    f = hv[slot];                                // guaranteed present & final
  }
  firsts[i] = f;
}

// Single block: rank = prefix sum of is_first (insertion order), then
// colors, out_colors, and the per-graph histogram counts in one pass.
// All reads linear/coalesced (firsts precomputed by k_lookup).
// Wave-level shfl scan: 2 barriers.
__global__ __launch_bounds__(1024) void k_scan(const int* __restrict__ firsts,
                                               const int* __restrict__ batch,
                                               float* __restrict__ out_colors,
                                               int* __restrict__ cnt) {
  __shared__ int rank_lds[NN];     // 64 KiB
  __shared__ int wsum[16];
  int t = threadIdx.x;
  int lane = t & 63, wv = t >> 6;
  int base = t * 16;
  int fidx[16];
  int loc[16];
  int s = 0;
  #pragma unroll
  for (int u = 0; u < 16; ++u) {
    int i = base + u;
    int f = firsts[i];
    fidx[u] = f;
    int isf = (f == i);
    s += isf;
    loc[u] = s;                    // inclusive within segment
  }
  // wave-inclusive scan of s
  int incl = s;
  #pragma unroll
  for (int off = 1; off < 64; off <<= 1) {
    int v = __shfl_up(incl, off, 64);
    if (lane >= off) incl += v;
  }
  if (lane == 63) wsum[wv] = incl;
  __syncthreads();
  if (t == 0) {
    int acc = 0;
    #pragma unroll
    for (int w = 0; w < 16; ++w) { int v = wsum[w]; wsum[w] = acc; acc += v; }
  }
  __syncthreads();
  int excl = wsum[wv] + incl - s;  // exclusive prefix of this thread's segment
  #pragma unroll
  for (int u = 0; u < 16; ++u) rank_lds[base + u] = excl + loc[u];
  __syncthreads();
  #pragma unroll
  for (int u = 0; u < 16; ++u) {
    int i = base + u;
    int c = (fidx[u] < 0) ? 0 : rank_lds[fidx[u]];
    out_colors[i] = (float)c;
    if (c > 0) atomicAdd(&cnt[(size_t)batch[i] * NN + (c - 1)], 1);
  }
}

__global__ __launch_bounds__(256) void k_norm(const int* __restrict__ cnt,
                                              float* __restrict__ out) {
  __shared__ float red[256];
  int b = blockIdx.x;
  const int4* c4 = (const int4*)(cnt + (size_t)b * NN);
  float4* o4 = (float4*)(out + (size_t)b * NN);
  float ss = 0.0f;
  for (int j = threadIdx.x; j < NN / 4; j += 256) {
    int4 v = c4[j];
    float4 f = {(float)v.x, (float)v.y, (float)v.z, (float)v.w};
    ss += f.x * f.x + f.y * f.y + f.z * f.z + f.w * f.w;
  }
  red[threadIdx.x] = ss;
  __syncthreads();
  for (int s = 128; s > 0; s >>= 1) {
    if (threadIdx.x < s) red[threadIdx.x] += red[threadIdx.x + s];
    __syncthreads();
  }
  float inv = 1.0f / sqrtf(red[0]);
  for (int j = threadIdx.x; j < NN / 4; j += 256) {
    int4 v = c4[j];
    float4 f = {(float)v.x * inv, (float)v.y * inv, (float)v.z * inv, (float)v.w * inv};
    o4[j] = f;
  }
}

// ---------------- host: numpy RandomState(42) MULTS replication ----------------

struct MTState { uint32_t mt[624]; int idx; };

static void mt_seed(MTState& s, uint32_t seed) {
  s.mt[0] = seed;
  for (int i = 1; i < 624; ++i)
    s.mt[i] = 1812433253u * (s.mt[i - 1] ^ (s.mt[i - 1] >> 30)) + (uint32_t)i;
  s.idx = 624;
}

static uint32_t mt_next(MTState& s) {
  if (s.idx >= 624) {
    for (int i = 0; i < 624; ++i) {
      uint32_t y = (s.mt[i] & 0x80000000u) | (s.mt[(i + 1) % 624] & 0x7fffffffu);
      uint32_t nx = s.mt[(i + 397) % 624] ^ (y >> 1);
      if (y & 1u) nx ^= 2567483615u;
      s.mt[i] = nx;
    }
    s.idx = 0;
  }
  uint32_t y = s.mt[s.idx++];
  y ^= y >> 11;
  y ^= (y << 7) & 2636928640u;
  y ^= (y << 15) & 4022730752u;
  y ^= y >> 18;
  return y;
}

static uint64_t mt_next64(MTState& s) {
  uint64_t hi = mt_next(s);
  uint64_t lo = mt_next(s);
  return (hi << 32) | lo;
}

// ---------------- launch ----------------

extern "C" void kernel_launch(void* const* d_in, const int* in_sizes, int n_in,
                              void* d_out, int out_size, void* d_ws, size_t ws_size,
                              hipStream_t stream) {
  const int*   x     = (const int*)d_in[0];
  const float* adj   = (const float*)d_in[1];
  const int*   batch = (const int*)d_in[2];
  float* out_hist   = (float*)d_out;                    // [NB, NN]
  float* out_colors = out_hist + (size_t)NB * NN;       // [NN]

  char* ws = (char*)d_ws;
  int*                cnt      = (int*)(ws + 0);          // 4 MiB
  int*                scount   = (int*)(ws + 4194304);    // 256 B
  int*                suspects = (int*)(ws + 4194560);    // 64 KiB
  unsigned long long* h        = (unsigned long long*)(ws + 4260096); // 128 KiB
  int*                iso      = (int*)(ws + 4391168);    // 64 KiB
  int*                firsts   = (int*)(ws + 4456704);    // 64 KiB
  unsigned long long* table    = (unsigned long long*)(ws + 4522240); // 32 KiB
  unsigned long long* hk       = (unsigned long long*)(ws + 4554752); // 512 KiB hash keys
  int*                hv       = (int*)(ws + 5079040);    // 256 KiB hash values (min idx)

  // Replicate np.random.RandomState(42).randint(1, 2**62, 17) << 1 | 1
  // (legacy masked rejection: mask = 2^62-1, accept <= 2^62-2, high word first)
  Mults M;
  {
    MTState st;
    mt_seed(st, 42u);
    const uint64_t mask62 = (1ull << 62) - 1ull;
    const uint64_t rng    = (1ull << 62) - 2ull;
    for (int i = 0; i < 17; ++i) {
      uint64_t v;
      do { v = mt_next64(st) & mask62; } while (v > rng);
      M.m[i] = ((1ull + v) << 1) | 1ull;
    }
  }

  k_init<<<256, 256, 0, stream>>>(x, table, scount, cnt, hk, hv);
  k_hist<<<NN / 4, 256, 0, stream>>>(adj, table, x, M, h, iso, suspects, scount, hk, hv);
  k_colcheck<<<64, 256, 0, stream>>>(adj, suspects, scount, iso, h, hk, hv);
  k_lookup<<<NN / 256, 256, 0, stream>>>(iso, h, hk, hv, firsts);
  k_scan<<<1, 1024, 0, stream>>>(firsts, batch, out_colors, cnt);
  k_norm<<<NB, 256, 0, stream>>>(cnt, out_hist);
}

// Round 3
// 1340.547 us; speedup vs baseline: 1.0655x; 1.0152x over previous
//
#include <hip/hip_runtime.h>
#include <stdint.h>

#define NN 16384   // nodes
#define NC 16      // colors
#define NB 64      // graphs

// open-addressing hash table: h (64-bit) -> min node index
#define HSIZE 65536
#define HMASK 65535
#define HSENT 0xFFFFFFFFFFFFFFFFull
#define HGOLD 0x9E3779B97F4A7C15ull

typedef unsigned int vuint4 __attribute__((ext_vector_type(4)));  // native vec for nontemporal builtin

struct Mults { unsigned long long m[17]; };

__device__ __forceinline__ void htab_insert(unsigned long long* __restrict__ hk,
                                            int* __restrict__ hv,
                                            unsigned long long key, int idx) {
  if (key == HSENT) key -= 1;                    // sentinel nudge (prob ~2^-64, same class risk as ref's 64-bit hash)
  unsigned slot = (unsigned)((key * HGOLD) >> 48);
  for (;;) {
    unsigned long long old = atomicCAS(&hk[slot], HSENT, key);
    if (old == HSENT || old == key) { atomicMin(&hv[slot], idx); return; }
    slot = (slot + 1) & HMASK;
  }
}

// ---------------- kernels ----------------

// Build per-64-column color bitmasks matching the ballot bit layout of k_hist,
// zero scount, zero the 4 MB cnt buffer, and init the hash table.
// grid = 256 x 256 threads.
__global__ __launch_bounds__(256) void k_init(const int* __restrict__ x,
                                              unsigned long long* __restrict__ table,
                                              int* __restrict__ scount,
                                              int* __restrict__ cnt,
                                              unsigned long long* __restrict__ hk,
                                              int* __restrict__ hv) {
  int idx = blockIdx.x * 256 + threadIdx.x;        // [0, 65536)
  if (idx == 0) *scount = 0;
  if (idx < 4096) {
    int c = idx & 15, k = (idx >> 4) & 3, chunk = idx >> 6;
    unsigned long long m = 0ull;
    for (int l = 0; l < 64; ++l) {
      int col = chunk * 256 + l * 4 + k;
      if (x[col] == c) m |= (1ull << l);
    }
    table[idx] = m;
  }
  // hash table init: 65536 slots, one per thread
  hk[idx] = HSENT;
  hv[idx] = 0x7fffffff;
  // zero cnt: 1M ints = 262144 int4; 65536 threads x 4 int4 each
  int4 z = {0, 0, 0, 0};
  int4* c4 = (int4*)cnt;
  #pragma unroll
  for (int r = 0; r < 4; ++r) c4[(size_t)idx * 4 + r] = z;
}

// One wave per row: neighbor color histogram via ballots + mask popcounts.
// Inner loop restructured into 8-chunk batches: all 8 nontemporal loads are
// issued before any ballot consumes them (static-indexed regs, full unroll)
// -> ~2x per-wave bytes in flight vs unroll-4, attacking the HBM-latency MLP
// shortfall (need ~9 KB/CU in flight for 6.3 TB/s; was ~2 KB/CU).
// Epilogue computes the 64-bit polynomial hash, rowsum (isolation suspects),
// inserts (h, row) into the hash table for non-suspect rows, and inits iso.
__global__ __launch_bounds__(256) void k_hist(const float* __restrict__ adj,
                                              const unsigned long long* __restrict__ table,
                                              const int* __restrict__ x,
                                              Mults M,
                                              unsigned long long* __restrict__ h,
                                              int* __restrict__ iso,
                                              int* __restrict__ suspects,
                                              int* __restrict__ scount,
                                              unsigned long long* __restrict__ hk,
                                              int* __restrict__ hv) {
  int wave = threadIdx.x >> 6;
  int lane = threadIdx.x & 63;
  int row  = blockIdx.x * 4 + wave;
  int xv   = x[row];
  const vuint4* rowp = (const vuint4*)(adj + (size_t)row * NN);
  int c = lane & 15;
  int k = lane >> 4;                               // k-slice 0..3
  const unsigned long long* tk = table + (k * 16 + c);
  int cnt = 0;
  for (int cc = 0; cc < 64; cc += 8) {
    vuint4 v[8];
    unsigned long long tm[8];
    #pragma unroll
    for (int u = 0; u < 8; ++u) {
      v[u]  = __builtin_nontemporal_load(&rowp[(cc + u) * 64 + lane]);  // 1 KiB/wave, coalesced, streamed
      tm[u] = tk[(cc + u) * 64];                                        // L1-resident (32 KiB table)
    }
    #pragma unroll
    for (int u = 0; u < 8; ++u) {
      unsigned long long b0 = __ballot(v[u].x != 0u);
      unsigned long long b1 = __ballot(v[u].y != 0u);
      unsigned long long b2 = __ballot(v[u].z != 0u);
      unsigned long long b3 = __ballot(v[u].w != 0u);
      unsigned long long m = (k & 2) ? ((k & 1) ? b3 : b2) : ((k & 1) ? b1 : b0);
      cnt += __popcll(m & tm[u]);
    }
  }
  // fold the 4 k-slices: every lane now holds hist[lane & 15]
  cnt += __shfl_xor(cnt, 16, 64);
  cnt += __shfl_xor(cnt, 32, 64);
  // rowsum (within each 16-lane group = sum over all 16 colors)
  int rs = cnt;
  rs += __shfl_xor(rs, 1, 64);
  rs += __shfl_xor(rs, 2, 64);
  rs += __shfl_xor(rs, 4, 64);
  rs += __shfl_xor(rs, 8, 64);
  // polynomial hash: sum over c of hist[c] * M[c+1]
  unsigned long long hl = (unsigned long long)(long long)cnt * M.m[(lane & 15) + 1];
  hl += __shfl_xor(hl, 1, 64);
  hl += __shfl_xor(hl, 2, 64);
  hl += __shfl_xor(hl, 4, 64);
  hl += __shfl_xor(hl, 8, 64);
  if (lane == 0) {
    unsigned long long hf = hl + (unsigned long long)(long long)xv * M.m[0];
    h[row] = hf;
    if (rs == 0) {
      int s = atomicAdd(scount, 1);
      suspects[s] = row;                 // h not final until colcheck; insert deferred there
    } else {
      htab_insert(hk, hv, hf, row);
    }
  }
  if (lane == 1) iso[row] = 0;
}

// Check columns of suspect nodes only (exits immediately if no suspects).
// Confirmed isolates get iso=1; unconfirmed suspects get their h inserted
// into the hash table (their h from k_hist is final).
__global__ __launch_bounds__(256) void k_colcheck(const float* __restrict__ adj,
                                                  const int* __restrict__ suspects,
                                                  const int* __restrict__ scount,
                                                  int* __restrict__ iso,
                                                  const unsigned long long* __restrict__ h,
                                                  unsigned long long* __restrict__ hk,
                                                  int* __restrict__ hv) {
  __shared__ int red[256];
  int nsus = *scount;
  for (int u = blockIdx.x; u < nsus; u += gridDim.x) {
    int col = suspects[u];
    int any = 0;
    for (int r = threadIdx.x; r < NN; r += 256)
      any |= (adj[(size_t)r * NN + col] != 0.0f);
    red[threadIdx.x] = any;
    __syncthreads();
    for (int s = 128; s > 0; s >>= 1) {
      if (threadIdx.x < s) red[threadIdx.x] |= red[threadIdx.x + s];
      __syncthreads();
    }
    if (threadIdx.x == 0) {
      if (red[0] == 0) iso[col] = 1;
      else             htab_insert(hk, hv, h[col], col);
    }
    __syncthreads();
  }
}

// Grid-parallel hash lookup: firsts[i] = min{ j : h[j]==h[i] } via one O(1)
// probe chain per node; -1 for isolates. 16384 threads across 64 blocks hide
// the scattered-load latency that a single-block probe loop cannot.
__global__ __launch_bounds__(256) void k_lookup(const int* __restrict__ iso,
                                                const unsigned long long* __restrict__ h,
                                                const unsigned long long* __restrict__ hk,
                                                const int* __restrict__ hv,
                                                int* __restrict__ firsts) {
  int i = blockIdx.x * 256 + threadIdx.x;
  int f = -1;
  if (!iso[i]) {
    unsigned long long key = h[i];
    if (key == HSENT) key -= 1;                  // must match insert-side nudge
    unsigned slot = (unsigned)((key * HGOLD) >> 48);
    unsigned long long kk = hk[slot];
    while (kk != key) { slot = (slot + 1) & HMASK; kk = hk[slot]; }
    f = hv[slot];                                // guaranteed present & final
  }
  firsts[i] = f;
}

// Single block: rank = prefix sum of is_first (insertion order), then
// colors, out_colors, and the per-graph histogram counts in one pass.
// All reads linear/coalesced (firsts precomputed by k_lookup).
// Wave-level shfl scan: 2 barriers.
__global__ __launch_bounds__(1024) void k_scan(const int* __restrict__ firsts,
                                               const int* __restrict__ batch,
                                               float* __restrict__ out_colors,
                                               int* __restrict__ cnt) {
  __shared__ int rank_lds[NN];     // 64 KiB
  __shared__ int wsum[16];
  int t = threadIdx.x;
  int lane = t & 63, wv = t >> 6;
  int base = t * 16;
  int fidx[16];
  int loc[16];
  int s = 0;
  #pragma unroll
  for (int u = 0; u < 16; ++u) {
    int i = base + u;
    int f = firsts[i];
    fidx[u] = f;
    int isf = (f == i);
    s += isf;
    loc[u] = s;                    // inclusive within segment
  }
  // wave-inclusive scan of s
  int incl = s;
  #pragma unroll
  for (int off = 1; off < 64; off <<= 1) {
    int v = __shfl_up(incl, off, 64);
    if (lane >= off) incl += v;
  }
  if (lane == 63) wsum[wv] = incl;
  __syncthreads();
  if (t == 0) {
    int acc = 0;
    #pragma unroll
    for (int w = 0; w < 16; ++w) { int v = wsum[w]; wsum[w] = acc; acc += v; }
  }
  __syncthreads();
  int excl = wsum[wv] + incl - s;  // exclusive prefix of this thread's segment
  #pragma unroll
  for (int u = 0; u < 16; ++u) rank_lds[base + u] = excl + loc[u];
  __syncthreads();
  #pragma unroll
  for (int u = 0; u < 16; ++u) {
    int i = base + u;
    int c = (fidx[u] < 0) ? 0 : rank_lds[fidx[u]];
    out_colors[i] = (float)c;
    if (c > 0) atomicAdd(&cnt[(size_t)batch[i] * NN + (c - 1)], 1);
  }
}

__global__ __launch_bounds__(256) void k_norm(const int* __restrict__ cnt,
                                              float* __restrict__ out) {
  __shared__ float red[256];
  int b = blockIdx.x;
  const int4* c4 = (const int4*)(cnt + (size_t)b * NN);
  float4* o4 = (float4*)(out + (size_t)b * NN);
  float ss = 0.0f;
  for (int j = threadIdx.x; j < NN / 4; j += 256) {
    int4 v = c4[j];
    float4 f = {(float)v.x, (float)v.y, (float)v.z, (float)v.w};
    ss += f.x * f.x + f.y * f.y + f.z * f.z + f.w * f.w;
  }
  red[threadIdx.x] = ss;
  __syncthreads();
  for (int s = 128; s > 0; s >>= 1) {
    if (threadIdx.x < s) red[threadIdx.x] += red[threadIdx.x + s];
    __syncthreads();
  }
  float inv = 1.0f / sqrtf(red[0]);
  for (int j = threadIdx.x; j < NN / 4; j += 256) {
    int4 v = c4[j];
    float4 f = {(float)v.x * inv, (float)v.y * inv, (float)v.z * inv, (float)v.w * inv};
    o4[j] = f;
  }
}

// ---------------- host: numpy RandomState(42) MULTS replication ----------------

struct MTState { uint32_t mt[624]; int idx; };

static void mt_seed(MTState& s, uint32_t seed) {
  s.mt[0] = seed;
  for (int i = 1; i < 624; ++i)
    s.mt[i] = 1812433253u * (s.mt[i - 1] ^ (s.mt[i - 1] >> 30)) + (uint32_t)i;
  s.idx = 624;
}

static uint32_t mt_next(MTState& s) {
  if (s.idx >= 624) {
    for (int i = 0; i < 624; ++i) {
      uint32_t y = (s.mt[i] & 0x80000000u) | (s.mt[(i + 1) % 624] & 0x7fffffffu);
      uint32_t nx = s.mt[(i + 397) % 624] ^ (y >> 1);
      if (y & 1u) nx ^= 2567483615u;
      s.mt[i] = nx;
    }
    s.idx = 0;
  }
  uint32_t y = s.mt[s.idx++];
  y ^= y >> 11;
  y ^= (y << 7) & 2636928640u;
  y ^= (y << 15) & 4022730752u;
  y ^= y >> 18;
  return y;
}

static uint64_t mt_next64(MTState& s) {
  uint64_t hi = mt_next(s);
  uint64_t lo = mt_next(s);
  return (hi << 32) | lo;
}

// ---------------- launch ----------------

extern "C" void kernel_launch(void* const* d_in, const int* in_sizes, int n_in,
                              void* d_out, int out_size, void* d_ws, size_t ws_size,
                              hipStream_t stream) {
  const int*   x     = (const int*)d_in[0];
  const float* adj   = (const float*)d_in[1];
  const int*   batch = (const int*)d_in[2];
  float* out_hist   = (float*)d_out;                    // [NB, NN]
  float* out_colors = out_hist + (size_t)NB * NN;       // [NN]

  char* ws = (char*)d_ws;
  int*                cnt      = (int*)(ws + 0);          // 4 MiB
  int*                scount   = (int*)(ws + 4194304);    // 256 B
  int*                suspects = (int*)(ws + 4194560);    // 64 KiB
  unsigned long long* h        = (unsigned long long*)(ws + 4260096); // 128 KiB
  int*                iso      = (int*)(ws + 4391168);    // 64 KiB
  int*                firsts   = (int*)(ws + 4456704);    // 64 KiB
  unsigned long long* table    = (unsigned long long*)(ws + 4522240); // 32 KiB
  unsigned long long* hk       = (unsigned long long*)(ws + 4554752); // 512 KiB hash keys
  int*                hv       = (int*)(ws + 5079040);    // 256 KiB hash values (min idx)

  // Replicate np.random.RandomState(42).randint(1, 2**62, 17) << 1 | 1
  // (legacy masked rejection: mask = 2^62-1, accept <= 2^62-2, high word first)
  Mults M;
  {
    MTState st;
    mt_seed(st, 42u);
    const uint64_t mask62 = (1ull << 62) - 1ull;
    const uint64_t rng    = (1ull << 62) - 2ull;
    for (int i = 0; i < 17; ++i) {
      uint64_t v;
      do { v = mt_next64(st) & mask62; } while (v > rng);
      M.m[i] = ((1ull + v) << 1) | 1ull;
    }
  }

  k_init<<<256, 256, 0, stream>>>(x, table, scount, cnt, hk, hv);
  k_hist<<<NN / 4, 256, 0, stream>>>(adj, table, x, M, h, iso, suspects, scount, hk, hv);
  k_colcheck<<<64, 256, 0, stream>>>(adj, suspects, scount, iso, h, hk, hv);
  k_lookup<<<NN / 256, 256, 0, stream>>>(iso, h, hk, hv, firsts);
  k_scan<<<1, 1024, 0, stream>>>(firsts, batch, out_colors, cnt);
  k_norm<<<NB, 256, 0, stream>>>(cnt, out_hist);
}